// Round 9
// baseline (98.481 us; speedup 1.0000x reference)
//
#include <hip/hip_runtime.h>

#define N_ROWS 16384
#define L_DIM  4096
#define CG     16                 // locations per bucket (64B full-line W reads)
#define JT     512                // j columns per phase
#define NPH    4                  // phases per block (block covers 2048 j)
#define PITCH  (JT + 4)           // 516 floats: 16B-aligned, conflict-free b128
#define CAP    384                // list capacity (bucket ~Poisson(64), max ~110)

typedef float f32x4 __attribute__((ext_vector_type(4)));

// out[i, j] = z[i, w[i]] * W[j, w[i]] + b[j]
// R9: persistent bucket-blocks. Grid 512 = (256 buckets x 2 j-halves), all
// co-resident at 2 blocks/CU (single scheduling round). Each block scans w
// ONCE, gathers zw ONCE, then streams 4 j-phases with a double-buffered W
// tile: register-prefetch tile t+1 while storing tile t (nt), ds_write after
// the barrier. Store pipe idles only during the one ~3us prologue.
__global__ __launch_bounds__(256, 2) void pnet_fused(
    const int* __restrict__ w,
    const float* __restrict__ z,
    const float* __restrict__ W,
    const float* __restrict__ b,
    float* __restrict__ out)
{
    __shared__ float tile[2][CG * PITCH];   // 2 x 32.2 KB
    __shared__ int   list[CAP];             // i | (c<<16)
    __shared__ float zlist[CAP];
    __shared__ int   cnt;

    const int tid   = threadIdx.x;
    const int g     = blockIdx.x >> 1;
    const int half  = blockIdx.x & 1;
    const int l0    = g * CG;
    const int jh    = half * (NPH * JT);    // j-half base
    const int wid   = tid >> 6;
    const int lane  = tid & 63;
    const int q     = tid & 3;              // 16B chunk within the 64B row segment
    const int rbase = tid >> 2;             // tile row, step 64

    if (tid == 0) cnt = 0;

    f32x4 pf[8];   // register prefetch: 32 KB tile / 256 threads = 8 float4

#define PF_ISSUE(t)                                                            \
    {                                                                          \
        _Pragma("unroll")                                                      \
        for (int it = 0; it < 8; ++it) {                                       \
            const int r = rbase + it * 64;                                     \
            pf[it] = __builtin_nontemporal_load((const f32x4*)                 \
                &W[(size_t)(jh + (t) * JT + r) * L_DIM + l0 + 4 * q]);         \
        }                                                                      \
    }

#define DSWRITE(buf)                                                           \
    {                                                                          \
        _Pragma("unroll")                                                      \
        for (int it = 0; it < 8; ++it) {                                       \
            const int r = rbase + it * 64;                                     \
            tile[buf][(4 * q + 0) * PITCH + r] = pf[it].x;                     \
            tile[buf][(4 * q + 1) * PITCH + r] = pf[it].y;                     \
            tile[buf][(4 * q + 2) * PITCH + r] = pf[it].z;                     \
            tile[buf][(4 * q + 3) * PITCH + r] = pf[it].w;                     \
        }                                                                      \
    }

    // ---- issue phase-0 tile loads; scan w[] while they fly ----
    PF_ISSUE(0);
    __builtin_amdgcn_sched_barrier(0);

    #pragma unroll
    for (int s = 0; s < N_ROWS / 1024; ++s) {
        const int i0  = s * 1024 + tid * 4;
        const int4 wv = *(const int4*)&w[i0];
        const int vals[4] = {wv.x, wv.y, wv.z, wv.w};
        #pragma unroll
        for (int e = 0; e < 4; ++e) {
            const unsigned c = (unsigned)(vals[e] - l0);
            if (c < CG) {
                const int pos = atomicAdd(&cnt, 1);
                if (pos < CAP) list[pos] = (i0 + e) | ((int)c << 16);
            }
        }
    }
    __syncthreads();  // list + cnt final
    const int n     = cnt;
    const int nmain = n < CAP ? n : CAP;

    if (n <= CAP) {
        // ---- coop zw gather (all loads in flight) + phase-0 tile to LDS ----
        for (int e = tid; e < nmain; e += 256) {
            const int ent = list[e];
            zlist[e] = z[(unsigned)((ent & 0xFFFF) * L_DIM) + (unsigned)(ent >> 16) + l0];
        }
        DSWRITE(0);
        __syncthreads();  // tile[0] + zlist ready

        for (int t = 0; t < NPH; ++t) {
            const int cur = t & 1;
            if (t + 1 < NPH) {
                PF_ISSUE(t + 1);                      // fire next tile's loads
                __builtin_amdgcn_sched_barrier(0);    // keep them above the stream
            }
            const int j0 = jh + t * JT;
            const f32x4 bv0 = *(const f32x4*)&b[j0 + lane * 4];
            const f32x4 bv1 = *(const f32x4*)&b[j0 + lane * 4 + 256];

            // ---- stream: 2 ds_read_b128 + 8 fma + 2 nt 16B stores per row ----
            for (int e = wid; e < nmain; e += 4) {
                const int   ent = list[e];
                const int   i   = ent & 0xFFFF;
                const int   c   = ent >> 16;
                const float zw  = zlist[e];
                const f32x4 w0  = *(const f32x4*)&tile[cur][c * PITCH + lane * 4];
                const f32x4 w1  = *(const f32x4*)&tile[cur][c * PITCH + lane * 4 + 256];
                f32x4 o0, o1;
                o0.x = fmaf(zw, w0.x, bv0.x);
                o0.y = fmaf(zw, w0.y, bv0.y);
                o0.z = fmaf(zw, w0.z, bv0.z);
                o0.w = fmaf(zw, w0.w, bv0.w);
                o1.x = fmaf(zw, w1.x, bv1.x);
                o1.y = fmaf(zw, w1.y, bv1.y);
                o1.z = fmaf(zw, w1.z, bv1.z);
                o1.w = fmaf(zw, w1.w, bv1.w);
                const unsigned base = (unsigned)(i * L_DIM) + j0 + lane * 4;
                __builtin_nontemporal_store(o0, (f32x4*)&out[base]);
                __builtin_nontemporal_store(o1, (f32x4*)&out[base + 256]);
            }
            __syncthreads();                          // done reading tile[cur]
            if (t + 1 < NPH) {
                DSWRITE(cur ^ 1);                     // regs -> other buffer
                __syncthreads();                      // next tile ready
            }
        }
    } else {
        // ---- overflow fallback (unreachable for this input; correct always) ----
        // Phase tile staged single-buffered; w re-scanned in 256-row passes.
        DSWRITE(0);
        for (int t = 0; t < NPH; ++t) {
            if (t > 0) {
                __syncthreads();
                PF_ISSUE(t);
                DSWRITE(0);
            }
            __syncthreads();
            const int j0 = jh + t * JT;
            const f32x4 bv0 = *(const f32x4*)&b[j0 + lane * 4];
            const f32x4 bv1 = *(const f32x4*)&b[j0 + lane * 4 + 256];
            for (int base0 = 0; base0 < N_ROWS; base0 += 256) {
                __syncthreads();
                if (tid == 0) cnt = 0;
                __syncthreads();
                const int i  = base0 + tid;
                const int wi = w[i];
                const unsigned c = (unsigned)(wi - l0);
                if (c < CG) {
                    const int pos = atomicAdd(&cnt, 1);   // <=256 <= CAP
                    list[pos]  = i | ((int)c << 16);
                    zlist[pos] = z[(size_t)i * L_DIM + wi];
                }
                __syncthreads();
                const int np = cnt;
                for (int e = wid; e < np; e += 4) {
                    const int   ent = list[e];
                    const int   ii  = ent & 0xFFFF;
                    const int   c2  = ent >> 16;
                    const float zw  = zlist[e];
                    const f32x4 w0  = *(const f32x4*)&tile[0][c2 * PITCH + lane * 4];
                    const f32x4 w1  = *(const f32x4*)&tile[0][c2 * PITCH + lane * 4 + 256];
                    f32x4 o0, o1;
                    o0.x = fmaf(zw, w0.x, bv0.x);
                    o0.y = fmaf(zw, w0.y, bv0.y);
                    o0.z = fmaf(zw, w0.z, bv0.z);
                    o0.w = fmaf(zw, w0.w, bv0.w);
                    o1.x = fmaf(zw, w1.x, bv1.x);
                    o1.y = fmaf(zw, w1.y, bv1.y);
                    o1.z = fmaf(zw, w1.z, bv1.z);
                    o1.w = fmaf(zw, w1.w, bv1.w);
                    const unsigned base = (unsigned)(ii * L_DIM) + j0 + lane * 4;
                    *(f32x4*)&out[base]       = o0;
                    *(f32x4*)&out[base + 256] = o1;
                }
            }
        }
    }
#undef PF_ISSUE
#undef DSWRITE
}

extern "C" void kernel_launch(void* const* d_in, const int* in_sizes, int n_in,
                              void* d_out, int out_size, void* d_ws, size_t ws_size,
                              hipStream_t stream) {
    const int*   w = (const int*)d_in[0];
    const float* z = (const float*)d_in[1];
    const float* W = (const float*)d_in[2];
    const float* b = (const float*)d_in[3];
    float* out = (float*)d_out;

    pnet_fused<<<512, 256, 0, stream>>>(w, z, W, b, out);  // all co-resident
}

// Round 10
// 79.324 us; speedup vs baseline: 1.2415x; 1.2415x over previous
//
#include <hip/hip_runtime.h>

#define N_ROWS 16384
#define L_DIM  4096
#define CG     16                 // locations per bucket (64B full-line W reads)
#define JT     2048               // j columns per block -> 8KB contiguous stores/row
#define PITCH  (JT + 4)           // 16B-aligned, conflict-free b128 reads
#define CAP    384                // list capacity (bucket ~Poisson(64), max ~110)

typedef float f32x4 __attribute__((ext_vector_type(4)));

// out[i, j] = z[i, w[i]] * W[j, w[i]] + b[j]
// R10: store-granularity probe. R8 structure, JT 1024 -> 2048: each matched
// row is stored as ONE 8KB contiguous chunk by one wave (was 4KB). LDS 131KB
// -> 1 block/CU, grid 512 = 2 rounds. Tests the HBM row-buffer-thrash theory
// for the ~4.5 TB/s steady-state plateau.
__global__ __launch_bounds__(256, 1) void pnet_fused(
    const int* __restrict__ w,
    const float* __restrict__ z,
    const float* __restrict__ W,
    const float* __restrict__ b,
    float* __restrict__ out)
{
    __shared__ float tile[CG * PITCH];   // 131.3 KB: tile[c*PITCH + r] = W[j0+r][l0+c]
    __shared__ int   list[CAP];          // i | (c<<16)
    __shared__ float zlist[CAP];
    __shared__ int   cnt;

    const int tid  = threadIdx.x;
    const int g    = blockIdx.x >> 1;
    const int l0   = g * CG;
    const int j0   = (blockIdx.x & 1) * JT;
    const int wid  = tid >> 6;
    const int lane = tid & 63;

    if (tid == 0) cnt = 0;

    // per-lane bias fragment: row chunk k covers j = j0 + k*256 + lane*4
    f32x4 bb[JT / 256];
    #pragma unroll
    for (int k = 0; k < JT / 256; ++k)
        bb[k] = *(const f32x4*)&b[j0 + k * 256 + lane * 4];

    __syncthreads();  // cnt ready

    // ---- stage W tile: coalesced 64B-line reads, transposed LDS writes ----
    {
        const int q     = tid & 3;        // 16B chunk within the 64B row segment
        const int rbase = tid >> 2;       // tile row, step 64
        #pragma unroll
        for (int it = 0; it < JT / 64; ++it) {
            const int r = rbase + it * 64;
            const f32x4 v = *(const f32x4*)&W[(size_t)(j0 + r) * L_DIM + l0 + 4 * q];
            tile[(4 * q + 0) * PITCH + r] = v.x;
            tile[(4 * q + 1) * PITCH + r] = v.y;
            tile[(4 * q + 2) * PITCH + r] = v.z;
            tile[(4 * q + 3) * PITCH + r] = v.w;
        }
    }

    // ---- scan w[] once: append packed entries (L2-fast, no gathers) ----
    #pragma unroll
    for (int s = 0; s < N_ROWS / 1024; ++s) {
        const int i0  = s * 1024 + tid * 4;
        const int4 wv = *(const int4*)&w[i0];
        const int vals[4] = {wv.x, wv.y, wv.z, wv.w};
        #pragma unroll
        for (int e = 0; e < 4; ++e) {
            const unsigned c = (unsigned)(vals[e] - l0);
            if (c < CG) {
                const int pos = atomicAdd(&cnt, 1);
                if (pos < CAP) list[pos] = (i0 + e) | ((int)c << 16);
            }
        }
    }
    __syncthreads();  // tile + list ready
    const int n     = cnt;
    const int nmain = n < CAP ? n : CAP;

    // ---- cooperative zw gather: all loads in flight simultaneously ----
    for (int e = tid; e < nmain; e += 256) {
        const int ent = list[e];
        zlist[e] = z[(unsigned)((ent & 0xFFFF) * L_DIM) + (unsigned)(ent >> 16) + l0];
    }
    __syncthreads();  // zlist ready

    // ---- stream: one wave stores one row's 8KB contiguously; no barriers ----
    for (int e = wid; e < nmain; e += 4) {
        const int   ent = list[e];
        const int   i   = ent & 0xFFFF;
        const int   c   = ent >> 16;
        const float zw  = zlist[e];
        const float* __restrict__ trow = &tile[c * PITCH];
        float*       __restrict__ orow = &out[(unsigned)(i * L_DIM) + j0];
        #pragma unroll
        for (int k = 0; k < JT / 256; ++k) {
            const int jj = k * 256 + lane * 4;
            const f32x4 wv4 = *(const f32x4*)&trow[jj];   // ds_read_b128, conflict-free
            f32x4 o;
            o.x = fmaf(zw, wv4.x, bb[k].x);
            o.y = fmaf(zw, wv4.y, bb[k].y);
            o.z = fmaf(zw, wv4.z, bb[k].z);
            o.w = fmaf(zw, wv4.w, bb[k].w);
            __builtin_nontemporal_store(o, (f32x4*)&orow[jj]);
        }
    }

    // ---- overflow fallback (unreachable for this input; correct for any input) ----
    if (n > CAP) {
        for (int p = 0; p < N_ROWS / 256; ++p) {
            __syncthreads();
            if (tid == 0) cnt = 0;
            __syncthreads();
            const int i  = p * 256 + tid;
            const int wi = w[i];
            const unsigned c = (unsigned)(wi - l0);
            if (c < CG) {
                const int pos = atomicAdd(&cnt, 1);   // <=256 <= CAP
                list[pos]  = i | ((int)c << 16);
                zlist[pos] = z[(size_t)i * L_DIM + wi];
            }
            __syncthreads();
            const int np = cnt;
            for (int e = wid; e < np; e += 4) {
                const int   ent = list[e];
                const int   ii  = ent & 0xFFFF;
                const int   c2  = ent >> 16;
                const float zw  = zlist[e];
                const float* __restrict__ trow = &tile[c2 * PITCH];
                float*       __restrict__ orow = &out[(unsigned)(ii * L_DIM) + j0];
                #pragma unroll
                for (int k = 0; k < JT / 256; ++k) {
                    const int jj = k * 256 + lane * 4;
                    const f32x4 wv4 = *(const f32x4*)&trow[jj];
                    f32x4 o;
                    o.x = fmaf(zw, wv4.x, bb[k].x);
                    o.y = fmaf(zw, wv4.y, bb[k].y);
                    o.z = fmaf(zw, wv4.z, bb[k].z);
                    o.w = fmaf(zw, wv4.w, bb[k].w);
                    *(f32x4*)&orow[jj] = o;
                }
            }
        }
    }
}

extern "C" void kernel_launch(void* const* d_in, const int* in_sizes, int n_in,
                              void* d_out, int out_size, void* d_ws, size_t ws_size,
                              hipStream_t stream) {
    const int*   w = (const int*)d_in[0];
    const float* z = (const float*)d_in[1];
    const float* W = (const float*)d_in[2];
    const float* b = (const float*)d_in[3];
    float* out = (float*)d_out;

    pnet_fused<<<512, 256, 0, stream>>>(w, z, W, b, out);  // (256 buckets x 2 halves)
}